// Round 4
// baseline (142.403 us; speedup 1.0000x reference)
//
#include <hip/hip_runtime.h>
#include <hip/hip_bf16.h>
#include <stdint.h>

#define TEMPERATURE 0.07f

constexpr int NQ = 256;
constexpr int KQ = 8192;
constexpr int D  = 128;
constexpr int N  = NQ + 2 * KQ;   // 16640
constexpr int CS = 32;            // column splits
constexpr int BN = 64;            // columns per tile
constexpr int NT = N / BN;        // 260 column tiles
constexpr int RBS = N / 256;      // 65 row blocks

typedef short  s16x8  __attribute__((ext_vector_type(8)));
typedef float  f32x16 __attribute__((ext_vector_type(16)));

// ---- workspace layout (bytes) ----
constexpr size_t OFF_F32  = 0;                                    // float feat [N][D]
constexpr size_t OFF_BF16 = OFF_F32  + (size_t)N * D * 4;         // bf16 feat  [N][D]
constexpr size_t OFF_PART = OFF_BF16 + (size_t)N * D * 2;         // partials   [N][CS]
constexpr size_t OFF_LP   = OFF_PART + (size_t)N * CS * 4;        // label partials [260][2][128]
constexpr size_t OFF_S    = OFF_LP   + (size_t)260 * 2 * 128 * 4; // S [2][128]
constexpr size_t OFF_CNT  = OFF_S    + 2 * 128 * 4;               // counts [2] int
constexpr size_t OFF_BSUM = OFF_CNT  + 16;                        // blocksum [65]

// ---------------------------------------------------------------------------
// K1: build normalized feature matrix (f32 + bf16). One wave per row.
// ---------------------------------------------------------------------------
__global__ __launch_bounds__(256) void k_prep(const float* __restrict__ q,
                                              const float* __restrict__ ba,
                                              const float* __restrict__ nb,
                                              float* __restrict__ ff,
                                              unsigned short* __restrict__ fb) {
    int wid = threadIdx.x >> 6, lane = threadIdx.x & 63;
    int r = blockIdx.x * 4 + wid;
    const float* src = (r < NQ) ? (q + (size_t)r * D)
                     : (r < NQ + KQ) ? (ba + (size_t)(r - NQ) * D)
                     : (nb + (size_t)(r - NQ - KQ) * D);
    float2 v = *(const float2*)(src + lane * 2);
    float scale = 1.0f;
    if (r < NQ) {
        float ss = v.x * v.x + v.y * v.y;
        #pragma unroll
        for (int m = 1; m < 64; m <<= 1) ss += __shfl_xor(ss, m);
        float nrm = sqrtf(ss);
        nrm = fmaxf(nrm, 1e-12f);
        scale = 1.0f / nrm;
    }
    float a = v.x * scale, b = v.y * scale;
    *(float2*)(ff + (size_t)r * D + lane * 2) = make_float2(a, b);
    unsigned int ua = __float_as_uint(a);
    ua = (ua + 0x7fffu + ((ua >> 16) & 1u)) >> 16;
    unsigned int ub = __float_as_uint(b);
    ub = (ub + 0x7fffu + ((ub >> 16) & 1u)) >> 16;
    *(unsigned int*)(fb + (size_t)r * D + lane * 2) = ua | (ub << 16);
}

// ---------------------------------------------------------------------------
// K2a: per-label column sums, stage 1 (deterministic). 260 blocks x 64 rows.
// ---------------------------------------------------------------------------
__global__ __launch_bounds__(128) void k_lsum_a(const float* __restrict__ ff,
                                                const long long* __restrict__ tgt,
                                                float* __restrict__ lp) {
    int d = threadIdx.x;
    int r0 = blockIdx.x * 64;
    float p0 = 0.f, p1 = 0.f;
    #pragma unroll 4
    for (int i = 0; i < 64; ++i) {
        int r = r0 + i;
        float v = ff[(size_t)r * D + d];
        int lab = (r < NQ) ? (int)tgt[r] : ((r < NQ + KQ) ? 1 : 0);
        if (lab) p1 += v; else p0 += v;
    }
    lp[((size_t)blockIdx.x * 2 + 0) * 128 + d] = p0;
    lp[((size_t)blockIdx.x * 2 + 1) * 128 + d] = p1;
}

// ---------------------------------------------------------------------------
// K2b: stage 2 reduction + label counts.
// ---------------------------------------------------------------------------
__global__ __launch_bounds__(256) void k_lsum_b(const float* __restrict__ lp,
                                                const long long* __restrict__ tgt,
                                                float* __restrict__ S,
                                                int* __restrict__ cnt) {
    int lab = threadIdx.x >> 7;       // 0 or 1
    int d   = threadIdx.x & 127;
    float s = 0.f;
    #pragma unroll 4
    for (int b = 0; b < 260; ++b)
        s += lp[((size_t)b * 2 + lab) * 128 + d];
    S[lab * 128 + d] = s;
    if (threadIdx.x < 64) {
        int c = 0;
        #pragma unroll
        for (int i = 0; i < 4; ++i) c += (int)tgt[threadIdx.x + 64 * i];
        #pragma unroll
        for (int m = 1; m < 64; m <<= 1) c += __shfl_xor(c, m);
        if (threadIdx.x == 0) { cnt[0] = (NQ - c) + KQ; cnt[1] = c + KQ; }
    }
}

// ---------------------------------------------------------------------------
// K3: main fused GEMM + exp row-sum.
//   Grid 65*32 = 2080 blocks, 512 threads (8 waves x 32 rows).
//   Double-buffered LDS via global_load_lds (linear dest, swizzled source).
//   Swapped MFMA: D[c][r] = colfeat . rowfeat^T so lane l owns row (l&31).
// ---------------------------------------------------------------------------
__global__ __launch_bounds__(512, 4) void k_main(const unsigned short* __restrict__ fb,
                                                 float* __restrict__ part) {
    __shared__ __align__(16) unsigned char lds[2][BN * 256];   // 2 x 16KB
    const int bid = blockIdx.x;
    const int rb = bid / CS, cs = bid % CS;
    const int tid = threadIdx.x;
    const int lane = tid & 63;
    const int wid  = tid >> 6;                 // 0..7
    const int l31 = lane & 31, lhi = lane >> 5;
    const int rw = rb * 256 + wid * 32;        // this wave's 32 rows

    // staging: per-lane global source byte offsets within a tile.
    // LDS dest is linear (base + lane*16); swizzle applied to the SOURCE so
    // the swizzled READ below finds the right bytes (rule: both-sides-or-neither).
    int srcoff[2];
    #pragma unroll
    for (int c = 0; c < 2; ++c) {
        int row = wid * 8 + c * 4 + (lane >> 4);
        srcoff[c] = row * 256 + (((lane & 15) << 4) ^ ((row & 15) << 4));
    }
    const char* fbb = (const char*)fb;

    // row fragments (B operand): 32 rows/wave, K=128 -> 8 ksteps x 16B
    s16x8 rf[8];
    #pragma unroll
    for (int ks = 0; ks < 8; ++ks)
        rf[ks] = *(const s16x8*)(fb + (size_t)(rw + l31) * D + ks * 16 + lhi * 8);

    const float sc = 1.4426950408889634f / TEMPERATURE;   // log2(e)/T
    float rsum = 0.f;
    const int ntiles = (cs < (NT % CS)) ? (NT / CS + 1) : (NT / CS);

    // prologue: stage tile 0 into buf 0
    {
        const char* base = fbb + (size_t)cs * 16384;
        #pragma unroll
        for (int c = 0; c < 2; ++c)
            __builtin_amdgcn_global_load_lds(
                (const __attribute__((address_space(1))) unsigned int*)(base + srcoff[c]),
                (__attribute__((address_space(3))) unsigned int*)(&lds[0][(wid * 8 + c * 4) * 256]),
                16, 0, 0);
    }
    asm volatile("s_waitcnt vmcnt(0)" ::: "memory");
    __builtin_amdgcn_s_barrier();

    int cur = 0;
    for (int t = 0; t < ntiles; ++t) {
        int ct = cs + t * CS;

        // prefetch next tile into the other buffer (in flight across compute)
        if (t + 1 < ntiles) {
            const char* base = fbb + ((size_t)ct + CS) * 16384;
            #pragma unroll
            for (int c = 0; c < 2; ++c)
                __builtin_amdgcn_global_load_lds(
                    (const __attribute__((address_space(1))) unsigned int*)(base + srcoff[c]),
                    (__attribute__((address_space(3))) unsigned int*)(&lds[cur ^ 1][(wid * 8 + c * 4) * 256]),
                    16, 0, 0);
        }

        f32x16 acc[2];
        #pragma unroll
        for (int i = 0; i < 2; ++i)
            #pragma unroll
            for (int e = 0; e < 16; ++e) acc[i][e] = 0.f;

        #pragma unroll
        for (int ks = 0; ks < 8; ++ks) {
            #pragma unroll
            for (int cc = 0; cc < 2; ++cc) {
                int crow = cc * 32 + l31;
                s16x8 cf = *(const s16x8*)(&lds[cur][crow * 256 +
                               ((ks * 32 + lhi * 16) ^ ((crow & 15) << 4))]);
                acc[cc] = __builtin_amdgcn_mfma_f32_32x32x16_bf16(cf, rf[ks], acc[cc], 0, 0, 0);
            }
        }

        // epilogue: e = exp2(sim*log2e/T - log2e/T) = exp(sim/T - 1/T)
        int c0 = ct * BN;
        if ((unsigned)(ct - rb * 4) < 4u) {
            // diagonal tile: mask self-similarity per element
            int rg = rw + l31;
            #pragma unroll
            for (int cc = 0; cc < 2; ++cc) {
                float p = 0.f;
                #pragma unroll
                for (int g = 0; g < 16; ++g) {
                    int cg = c0 + cc * 32 + (g & 3) + ((g >> 2) << 3) + (lhi << 2);
                    float e = __builtin_amdgcn_exp2f(acc[cc][g] * sc - sc);
                    p += (cg == rg) ? 0.f : e;
                }
                rsum += p;
            }
        } else {
            #pragma unroll
            for (int cc = 0; cc < 2; ++cc) {
                float p = 0.f;
                #pragma unroll
                for (int g = 0; g < 16; ++g)
                    p += __builtin_amdgcn_exp2f(acc[cc][g] * sc - sc);
                rsum += p;
            }
        }

        // next tile's data landed (had the whole compute to fly); all waves aligned
        asm volatile("s_waitcnt vmcnt(0)" ::: "memory");
        __builtin_amdgcn_s_barrier();
        cur ^= 1;
    }

    // combine the two c-halves (lane and lane^32 hold same row, different cols)
    rsum += __shfl_xor(rsum, 32);
    if (lane < 32)
        part[(size_t)(rw + lane) * CS + cs] = rsum;
}

// ---------------------------------------------------------------------------
// K4: per-row finalize: LSE + positive term; block-reduce partial loss.
// ---------------------------------------------------------------------------
__global__ __launch_bounds__(256) void k_rowfin(const float* __restrict__ part,
                                                const float* __restrict__ ff,
                                                const float* __restrict__ S,
                                                const int* __restrict__ cnt,
                                                const long long* __restrict__ tgt,
                                                float* __restrict__ bsum) {
    __shared__ float sS[256];
    __shared__ float red[256];
    sS[threadIdx.x] = S[threadIdx.x];
    __syncthreads();
    int r = blockIdx.x * 256 + threadIdx.x;
    float se = 0.f;
    #pragma unroll
    for (int c = 0; c < CS; ++c) se += part[(size_t)r * CS + c];
    float lse = logf(se) + 1.0f / TEMPERATURE;
    int lab = (r < NQ) ? (int)tgt[r] : ((r < NQ + KQ) ? 1 : 0);
    const float4* frow = (const float4*)(ff + (size_t)r * D);
    const float4* srow = (const float4*)(sS + lab * 128);
    float dS = 0.f, dself = 0.f;
    #pragma unroll
    for (int i = 0; i < 32; ++i) {
        float4 f = frow[i];
        float4 s = srow[i];
        dS    += f.x * s.x + f.y * s.y + f.z * s.z + f.w * s.w;
        dself += f.x * f.x + f.y * f.y + f.z * f.z + f.w * f.w;
    }
    float P = (float)(cnt[lab] - 1);
    float mlpp = (dS - dself) / (TEMPERATURE * P) - lse;
    red[threadIdx.x] = mlpp;
    __syncthreads();
    for (int s2 = 128; s2 > 0; s2 >>= 1) {
        if (threadIdx.x < s2) red[threadIdx.x] += red[threadIdx.x + s2];
        __syncthreads();
    }
    if (threadIdx.x == 0) bsum[blockIdx.x] = red[0];
}

// ---------------------------------------------------------------------------
// K5: final scalar.
// ---------------------------------------------------------------------------
__global__ __launch_bounds__(64) void k_final(const float* __restrict__ bsum,
                                              float* __restrict__ out) {
    float s = bsum[threadIdx.x];                 // RBS=65 > 64, lanes 0..63 valid
    if (threadIdx.x == 0) s += bsum[64];
    #pragma unroll
    for (int m = 1; m < 64; m <<= 1) s += __shfl_xor(s, m);
    if (threadIdx.x == 0) out[0] = -s / (float)N;
}

extern "C" void kernel_launch(void* const* d_in, const int* in_sizes, int n_in,
                              void* d_out, int out_size, void* d_ws, size_t ws_size,
                              hipStream_t stream) {
    const float* q       = (const float*)d_in[0];
    const float* ba      = (const float*)d_in[1];
    const float* nb      = (const float*)d_in[2];
    const long long* tgt = (const long long*)d_in[3];
    char* ws = (char*)d_ws;
    float*          ff   = (float*)(ws + OFF_F32);
    unsigned short* fb   = (unsigned short*)(ws + OFF_BF16);
    float*          part = (float*)(ws + OFF_PART);
    float*          lp   = (float*)(ws + OFF_LP);
    float*          S    = (float*)(ws + OFF_S);
    int*            cnt  = (int*)(ws + OFF_CNT);
    float*          bsum = (float*)(ws + OFF_BSUM);

    k_prep  <<<N / 4, 256, 0, stream>>>(q, ba, nb, ff, fb);
    k_lsum_a<<<260,   128, 0, stream>>>(ff, tgt, lp);
    k_lsum_b<<<1,     256, 0, stream>>>(lp, tgt, S, cnt);
    k_main  <<<RBS * CS, 512, 0, stream>>>(fb, part);
    k_rowfin<<<RBS,   256, 0, stream>>>(part, ff, S, cnt, tgt, bsum);
    k_final <<<1,      64, 0, stream>>>(bsum, (float*)d_out);
}

// Round 5
// 125.180 us; speedup vs baseline: 1.1376x; 1.1376x over previous
//
#include <hip/hip_runtime.h>
#include <hip/hip_bf16.h>
#include <stdint.h>

#define TEMPERATURE 0.07f

constexpr int NQ = 256;
constexpr int KQ = 8192;
constexpr int D  = 128;
constexpr int N  = NQ + 2 * KQ;   // 16640
constexpr int CS = 26;            // column splits (130 tiles / 26 = exactly 5 per block)
constexpr int BN = 128;           // columns per tile
constexpr int NT = N / BN;        // 130 column tiles
constexpr int RBS = N / 256;      // 65 row blocks

typedef short  s16x8  __attribute__((ext_vector_type(8)));
typedef float  f32x16 __attribute__((ext_vector_type(16)));

// ---- workspace layout (bytes) ----
constexpr size_t OFF_F32  = 0;                                    // float feat [N][D]
constexpr size_t OFF_BF16 = OFF_F32  + (size_t)N * D * 4;         // bf16 feat  [N][D]
constexpr size_t OFF_PART = OFF_BF16 + (size_t)N * D * 2;         // partials   [N][<=32]
constexpr size_t OFF_LP   = OFF_PART + (size_t)N * 32 * 4;        // label partials [260][2][128]
constexpr size_t OFF_S    = OFF_LP   + (size_t)260 * 2 * 128 * 4; // S [2][128]
constexpr size_t OFF_CNT  = OFF_S    + 2 * 128 * 4;               // counts [2] int
constexpr size_t OFF_BSUM = OFF_CNT  + 16;                        // blocksum [65]

// ---------------------------------------------------------------------------
// K1: normalize features, emit f32 + bf16 copies, AND accumulate per-label
// per-dim partial sums (fused former k_lsum_a). 260 blocks x 64 rows.
// Blocks 0..3 are exactly the q rows (4*64=256): block-uniform norm branch.
// ---------------------------------------------------------------------------
__global__ __launch_bounds__(256) void k_prep(const float* __restrict__ q,
                                              const float* __restrict__ ba,
                                              const float* __restrict__ nb,
                                              const long long* __restrict__ tgt,
                                              float* __restrict__ ff,
                                              unsigned short* __restrict__ fb,
                                              float* __restrict__ lp) {
    __shared__ float red[4][2][128];
    int wid = threadIdx.x >> 6, lane = threadIdx.x & 63;
    int rbase = blockIdx.x * 64 + wid * 16;
    float s0x = 0.f, s0y = 0.f, s1x = 0.f, s1y = 0.f;
    for (int i = 0; i < 16; ++i) {
        int r = rbase + i;
        const float* src = (r < NQ) ? (q + (size_t)r * D)
                         : (r < NQ + KQ) ? (ba + (size_t)(r - NQ) * D)
                         : (nb + (size_t)(r - NQ - KQ) * D);
        float2 v = *(const float2*)(src + lane * 2);
        float a = v.x, b = v.y;
        int lab;
        if (r < NQ) {
            float ss = a * a + b * b;
            #pragma unroll
            for (int m = 1; m < 64; m <<= 1) ss += __shfl_xor(ss, m);
            float scale = 1.0f / fmaxf(sqrtf(ss), 1e-12f);
            a *= scale; b *= scale;
            lab = (int)tgt[r];
        } else {
            lab = (r < NQ + KQ) ? 1 : 0;
        }
        *(float2*)(ff + (size_t)r * D + lane * 2) = make_float2(a, b);
        unsigned int ua = __float_as_uint(a);
        ua = (ua + 0x7fffu + ((ua >> 16) & 1u)) >> 16;
        unsigned int ub = __float_as_uint(b);
        ub = (ub + 0x7fffu + ((ub >> 16) & 1u)) >> 16;
        *(unsigned int*)(fb + (size_t)r * D + lane * 2) = ua | (ub << 16);
        if (lab) { s1x += a; s1y += b; } else { s0x += a; s0y += b; }
    }
    red[wid][0][lane * 2]     = s0x;
    red[wid][0][lane * 2 + 1] = s0y;
    red[wid][1][lane * 2]     = s1x;
    red[wid][1][lane * 2 + 1] = s1y;
    __syncthreads();
    int lab = threadIdx.x >> 7, d = threadIdx.x & 127;
    float s = red[0][lab][d] + red[1][lab][d] + red[2][lab][d] + red[3][lab][d];
    lp[((size_t)blockIdx.x * 2 + lab) * 128 + d] = s;
}

// ---------------------------------------------------------------------------
// K2: stage-2 label-sum reduction + label counts.
// ---------------------------------------------------------------------------
__global__ __launch_bounds__(256) void k_lsum_b(const float* __restrict__ lp,
                                                const long long* __restrict__ tgt,
                                                float* __restrict__ S,
                                                int* __restrict__ cnt) {
    int lab = threadIdx.x >> 7;       // 0 or 1
    int d   = threadIdx.x & 127;
    float s[4] = {0.f, 0.f, 0.f, 0.f};
    for (int b = 0; b < 260; b += 4) {
        #pragma unroll
        for (int j = 0; j < 4; ++j)
            s[j] += lp[((size_t)(b + j) * 2 + lab) * 128 + d];
    }
    S[lab * 128 + d] = (s[0] + s[1]) + (s[2] + s[3]);
    if (threadIdx.x < 64) {
        int c = 0;
        #pragma unroll
        for (int i = 0; i < 4; ++i) c += (int)tgt[threadIdx.x + 64 * i];
        #pragma unroll
        for (int m = 1; m < 64; m <<= 1) c += __shfl_xor(c, m);
        if (threadIdx.x == 0) { cnt[0] = (NQ - c) + KQ; cnt[1] = c + KQ; }
    }
}

// ---------------------------------------------------------------------------
// K3: main fused GEMM + exp row-sum.
//   Grid 65*26 = 1690 blocks, 512 threads (8 waves x 32 rows).
//   BN=128 column tiles (32KB), double-buffered via global_load_lds
//   (linear LDS dest, XOR-swizzle applied to the global source address).
//   Exactly 5 tiles per block -> uniform work between barriers.
//   Swapped MFMA: D[c][r] = colfeat . rowfeat^T so lane l owns row (l&31).
// ---------------------------------------------------------------------------
__global__ __launch_bounds__(512, 2) void k_main(const unsigned short* __restrict__ fb,
                                                 float* __restrict__ part) {
    __shared__ __align__(16) unsigned char lds[2][BN * 256];   // 2 x 32KB
    const int bid = blockIdx.x;
    const int rb = bid / CS, cs = bid % CS;
    const int tid = threadIdx.x;
    const int lane = tid & 63;
    const int wid  = tid >> 6;                 // 0..7
    const int l31 = lane & 31, lhi = lane >> 5;
    const int rw = rb * 256 + wid * 32;        // this wave's 32 rows

    // staging: 4 chunks x 16B per thread; LDS dest linear, swizzled source.
    int srcoff[4], dstoff[4];
    #pragma unroll
    for (int c = 0; c < 4; ++c) {
        int flat = c * 512 + tid;
        int row = flat >> 4, col16 = flat & 15;
        srcoff[c] = row * 256 + ((col16 << 4) ^ ((row & 15) << 4));
        dstoff[c] = flat * 16;
    }
    const char* fbb = (const char*)fb;

    // row fragments (B operand): 32 rows/wave, K=128 -> 8 ksteps x 16B
    s16x8 rf[8];
    #pragma unroll
    for (int ks = 0; ks < 8; ++ks)
        rf[ks] = *(const s16x8*)(fb + (size_t)(rw + l31) * D + ks * 16 + lhi * 8);

    const float sc = 1.4426950408889634f / TEMPERATURE;   // log2(e)/T
    float rsum = 0.f;

    // prologue: stage tile 0 (ct = cs) into buf 0
    {
        const char* base = fbb + (size_t)cs * (BN * 256);
        #pragma unroll
        for (int c = 0; c < 4; ++c)
            __builtin_amdgcn_global_load_lds(
                (const __attribute__((address_space(1))) unsigned int*)(base + srcoff[c]),
                (__attribute__((address_space(3))) unsigned int*)(&lds[0][dstoff[c]]),
                16, 0, 0);
    }
    asm volatile("s_waitcnt vmcnt(0)" ::: "memory");
    __builtin_amdgcn_s_barrier();

    int cur = 0;
    for (int t = 0; t < 5; ++t) {
        int ct = cs + t * CS;

        // prefetch next tile into the other buffer (flies across whole phase)
        if (t + 1 < 5) {
            const char* base = fbb + ((size_t)ct + CS) * (BN * 256);
            #pragma unroll
            for (int c = 0; c < 4; ++c)
                __builtin_amdgcn_global_load_lds(
                    (const __attribute__((address_space(1))) unsigned int*)(base + srcoff[c]),
                    (__attribute__((address_space(3))) unsigned int*)(&lds[cur ^ 1][dstoff[c]]),
                    16, 0, 0);
        }

        f32x16 acc[4];
        #pragma unroll
        for (int i = 0; i < 4; ++i)
            #pragma unroll
            for (int e = 0; e < 16; ++e) acc[i][e] = 0.f;

        #pragma unroll
        for (int ks = 0; ks < 8; ++ks) {
            #pragma unroll
            for (int cc = 0; cc < 4; ++cc) {
                int crow = cc * 32 + l31;
                s16x8 cf = *(const s16x8*)(&lds[cur][crow * 256 +
                               ((ks * 32 + lhi * 16) ^ ((crow & 15) << 4))]);
                acc[cc] = __builtin_amdgcn_mfma_f32_32x32x16_bf16(cf, rf[ks], acc[cc], 0, 0, 0);
            }
        }

        // epilogue: e = exp2(sim*log2e/T - log2e/T) = exp(sim/T - 1/T)
        int c0 = ct * BN;
        if ((unsigned)(ct - rb * 2) < 2u) {
            // diagonal tile: mask self-similarity per element
            int rg = rw + l31;
            #pragma unroll
            for (int cc = 0; cc < 4; ++cc) {
                float p = 0.f;
                #pragma unroll
                for (int g = 0; g < 16; ++g) {
                    int cg = c0 + cc * 32 + (g & 3) + ((g >> 2) << 3) + (lhi << 2);
                    float e = __builtin_amdgcn_exp2f(acc[cc][g] * sc - sc);
                    p += (cg == rg) ? 0.f : e;
                }
                rsum += p;
            }
        } else {
            #pragma unroll
            for (int cc = 0; cc < 4; ++cc) {
                float p = 0.f;
                #pragma unroll
                for (int g = 0; g < 16; ++g)
                    p += __builtin_amdgcn_exp2f(acc[cc][g] * sc - sc);
                rsum += p;
            }
        }

        // next tile's loads landed (full phase of flight); re-align waves
        asm volatile("s_waitcnt vmcnt(0)" ::: "memory");
        __builtin_amdgcn_s_barrier();
        cur ^= 1;
    }

    // combine the two c-halves (lane and lane^32 hold same row, different cols)
    rsum += __shfl_xor(rsum, 32);
    if (lane < 32)
        part[(size_t)(rw + lane) * CS + cs] = rsum;
}

// ---------------------------------------------------------------------------
// K4: per-row finalize: LSE + positive term; block-reduce partial loss.
// ---------------------------------------------------------------------------
__global__ __launch_bounds__(256) void k_rowfin(const float* __restrict__ part,
                                                const float* __restrict__ ff,
                                                const float* __restrict__ S,
                                                const int* __restrict__ cnt,
                                                const long long* __restrict__ tgt,
                                                float* __restrict__ bsum) {
    __shared__ float sS[256];
    __shared__ float red[256];
    sS[threadIdx.x] = S[threadIdx.x];
    __syncthreads();
    int r = blockIdx.x * 256 + threadIdx.x;
    float se = 0.f;
    #pragma unroll
    for (int c = 0; c < CS; ++c) se += part[(size_t)r * CS + c];
    float lse = logf(se) + 1.0f / TEMPERATURE;
    int lab = (r < NQ) ? (int)tgt[r] : ((r < NQ + KQ) ? 1 : 0);
    const float4* frow = (const float4*)(ff + (size_t)r * D);
    const float4* srow = (const float4*)(sS + lab * 128);
    float dS = 0.f;
    #pragma unroll
    for (int i = 0; i < 32; ++i) {
        float4 f = frow[i];
        float4 s = srow[i];
        dS += f.x * s.x + f.y * s.y + f.z * s.z + f.w * s.w;
    }
    float P = (float)(cnt[lab] - 1);
    // ||f||^2 == 1 exactly (features L2-normalized in f32)
    float mlpp = (dS - 1.0f) / (TEMPERATURE * P) - lse;
    red[threadIdx.x] = mlpp;
    __syncthreads();
    for (int s2 = 128; s2 > 0; s2 >>= 1) {
        if (threadIdx.x < s2) red[threadIdx.x] += red[threadIdx.x + s2];
        __syncthreads();
    }
    if (threadIdx.x == 0) bsum[blockIdx.x] = red[0];
}

// ---------------------------------------------------------------------------
// K5: final scalar.
// ---------------------------------------------------------------------------
__global__ __launch_bounds__(64) void k_final(const float* __restrict__ bsum,
                                              float* __restrict__ out) {
    float s = bsum[threadIdx.x];                 // RBS=65 > 64, lanes 0..63 valid
    if (threadIdx.x == 0) s += bsum[64];
    #pragma unroll
    for (int m = 1; m < 64; m <<= 1) s += __shfl_xor(s, m);
    if (threadIdx.x == 0) out[0] = -s / (float)N;
}

extern "C" void kernel_launch(void* const* d_in, const int* in_sizes, int n_in,
                              void* d_out, int out_size, void* d_ws, size_t ws_size,
                              hipStream_t stream) {
    const float* q       = (const float*)d_in[0];
    const float* ba      = (const float*)d_in[1];
    const float* nb      = (const float*)d_in[2];
    const long long* tgt = (const long long*)d_in[3];
    char* ws = (char*)d_ws;
    float*          ff   = (float*)(ws + OFF_F32);
    unsigned short* fb   = (unsigned short*)(ws + OFF_BF16);
    float*          part = (float*)(ws + OFF_PART);
    float*          lp   = (float*)(ws + OFF_LP);
    float*          S    = (float*)(ws + OFF_S);
    int*            cnt  = (int*)(ws + OFF_CNT);
    float*          bsum = (float*)(ws + OFF_BSUM);

    k_prep  <<<260,   256, 0, stream>>>(q, ba, nb, tgt, ff, fb, lp);
    k_lsum_b<<<1,     256, 0, stream>>>(lp, tgt, S, cnt);
    k_main  <<<RBS * CS, 512, 0, stream>>>(fb, part);
    k_rowfin<<<RBS,   256, 0, stream>>>(part, ff, S, cnt, tgt, bsum);
    k_final <<<1,      64, 0, stream>>>(bsum, (float*)d_out);
}

// Round 6
// 96.214 us; speedup vs baseline: 1.4801x; 1.3011x over previous
//
#include <hip/hip_runtime.h>
#include <hip/hip_bf16.h>
#include <stdint.h>

#define TEMPERATURE 0.07f
#define SC 20.6099312f   // log2(e)/T

constexpr int NQ = 256;
constexpr int KQ = 8192;
constexpr int D  = 128;
constexpr int N  = NQ + 2 * KQ;   // 16640
constexpr int CS = 26;            // column splits (130 tiles / 26 = exactly 5 per block)
constexpr int BN = 128;           // columns per tile (fp8 tile = 16KB)
constexpr int NT = N / BN;        // 130 column tiles
constexpr int RBM = N / 128;      // 130 row blocks for k_main (128 rows each)
constexpr int RBF = N / 256;      // 65 blocks for k_rowfin

typedef float f32x16 __attribute__((ext_vector_type(16)));
typedef long  l64x2  __attribute__((ext_vector_type(2)));

// ---- workspace layout (bytes) ----
constexpr size_t OFF_F32  = 0;                                    // float feat [N][D]
constexpr size_t OFF_8P   = OFF_F32  + (size_t)N * D * 4;         // fp8 feat, k-permuted rows [N][128]
constexpr size_t OFF_8S   = OFF_8P   + (size_t)N * D;             // fp8 feat * SC, natural rows [N][128]
constexpr size_t OFF_DIAG = OFF_8S   + (size_t)N * D;             // diag exp term [N] f32
constexpr size_t OFF_PART = OFF_DIAG + (size_t)N * 4;             // partials [CS][N]
constexpr size_t OFF_LP   = OFF_PART + (size_t)CS * N * 4;        // label partials [260][2][128]
constexpr size_t OFF_S    = OFF_LP   + (size_t)260 * 2 * 128 * 4; // S [2][128]
constexpr size_t OFF_CNT  = OFF_S    + 2 * 128 * 4;               // counts [2] int
constexpr size_t OFF_BSUM = OFF_CNT  + 16;                        // blocksum [65]

// ---------------------------------------------------------------------------
// K1: normalize features; emit f32 + two fp8 copies (natural-scaled for rf,
// k-permuted for cf staging); per-row fp8 self-dot -> diag exp term; and
// per-label per-dim partial sums. 260 blocks x 64 rows, wave per row-slice.
// Row-byte permutation for fb8p (matches k_main's LDS slot layout):
//   k -> slot = ((k>>3)&1)*4 + (k>>5), h = (k>>4)&1, e = k&7
//   dest byte = slot*16 + h*8 + e
// ---------------------------------------------------------------------------
__global__ __launch_bounds__(256) void k_prep(const float* __restrict__ q,
                                              const float* __restrict__ ba,
                                              const float* __restrict__ nb,
                                              const long long* __restrict__ tgt,
                                              float* __restrict__ ff,
                                              unsigned char* __restrict__ fb8p,
                                              unsigned char* __restrict__ fb8s,
                                              float* __restrict__ diag,
                                              float* __restrict__ lp) {
    __shared__ float red[4][2][128];
    int wid = threadIdx.x >> 6, lane = threadIdx.x & 63;
    int rbase = blockIdx.x * 64 + wid * 16;
    // permuted byte offset for this lane's 2 dims (k = 2*lane, 2*lane+1)
    int slot = ((lane >> 2) & 1) * 4 + (lane >> 4);
    int poff = slot * 16 + ((lane >> 3) & 1) * 8 + (lane & 3) * 2;
    float s0x = 0.f, s0y = 0.f, s1x = 0.f, s1y = 0.f;
    for (int i = 0; i < 16; ++i) {
        int r = rbase + i;
        const float* src = (r < NQ) ? (q + (size_t)r * D)
                         : (r < NQ + KQ) ? (ba + (size_t)(r - NQ) * D)
                         : (nb + (size_t)(r - NQ - KQ) * D);
        float2 v = *(const float2*)(src + lane * 2);
        float a = v.x, b = v.y;
        int lab;
        if (r < NQ) {
            float ss = a * a + b * b;
            #pragma unroll
            for (int m = 1; m < 64; m <<= 1) ss += __shfl_xor(ss, m);
            float scale = 1.0f / fmaxf(sqrtf(ss), 1e-12f);
            a *= scale; b *= scale;
            lab = (int)tgt[r];
        } else {
            lab = (r < NQ + KQ) ? 1 : 0;
        }
        *(float2*)(ff + (size_t)r * D + lane * 2) = make_float2(a, b);
        int w8  = __builtin_amdgcn_cvt_pk_fp8_f32(a, b, 0, false);
        int w8s = __builtin_amdgcn_cvt_pk_fp8_f32(a * SC, b * SC, 0, false);
        *(unsigned short*)(fb8p + (size_t)r * D + poff)     = (unsigned short)w8;
        *(unsigned short*)(fb8s + (size_t)r * D + lane * 2) = (unsigned short)w8s;
        // fp8-exact replica of the MFMA self-similarity term
        float dd = __builtin_amdgcn_cvt_f32_fp8(w8, 0) * __builtin_amdgcn_cvt_f32_fp8(w8s, 0)
                 + __builtin_amdgcn_cvt_f32_fp8(w8, 1) * __builtin_amdgcn_cvt_f32_fp8(w8s, 1);
        #pragma unroll
        for (int m = 1; m < 64; m <<= 1) dd += __shfl_xor(dd, m);
        if (lane == 0) diag[r] = __builtin_amdgcn_exp2f(dd - SC);
        if (lab) { s1x += a; s1y += b; } else { s0x += a; s0y += b; }
    }
    red[wid][0][lane * 2]     = s0x;
    red[wid][0][lane * 2 + 1] = s0y;
    red[wid][1][lane * 2]     = s1x;
    red[wid][1][lane * 2 + 1] = s1y;
    __syncthreads();
    int lab2 = threadIdx.x >> 7, d = threadIdx.x & 127;
    float s = red[0][lab2][d] + red[1][lab2][d] + red[2][lab2][d] + red[3][lab2][d];
    lp[((size_t)blockIdx.x * 2 + lab2) * 128 + d] = s;
}

// ---------------------------------------------------------------------------
// K2: stage-2 label-sum reduction + label counts.
// ---------------------------------------------------------------------------
__global__ __launch_bounds__(256) void k_lsum_b(const float* __restrict__ lp,
                                                const long long* __restrict__ tgt,
                                                float* __restrict__ S,
                                                int* __restrict__ cnt) {
    int lab = threadIdx.x >> 7;       // 0 or 1
    int d   = threadIdx.x & 127;
    float s[4] = {0.f, 0.f, 0.f, 0.f};
    for (int b = 0; b < 260; b += 4) {
        #pragma unroll
        for (int j = 0; j < 4; ++j)
            s[j] += lp[((size_t)(b + j) * 2 + lab) * 128 + d];
    }
    S[lab * 128 + d] = (s[0] + s[1]) + (s[2] + s[3]);
    if (threadIdx.x < 64) {
        int c = 0;
        #pragma unroll
        for (int i = 0; i < 4; ++i) c += (int)tgt[threadIdx.x + 64 * i];
        #pragma unroll
        for (int m = 1; m < 64; m <<= 1) c += __shfl_xor(c, m);
        if (threadIdx.x == 0) { cnt[0] = (NQ - c) + KQ; cnt[1] = c + KQ; }
    }
}

// ---------------------------------------------------------------------------
// K3: main fused fp8 GEMM + exp row-sum.
//   Grid 130*26 = 3380 blocks, 256 threads (4 waves x 32 rows = 128 rows).
//   fp8 e4m3 MFMA 32x32x16; rf side pre-scaled by SC; acc init = -SC so the
//   epilogue is a bare v_exp. Diagonal handled later via diag[] (no branch).
//   LDS: 2 x 16KB dbuf; rows 128B, 16B slots XOR-swizzled by (crow&7); each
//   ds_read_b128 feeds 2 MFMAs (k-pair permuted row layout, see k_prep).
// ---------------------------------------------------------------------------
__global__ __launch_bounds__(256, 4) void k_main(const unsigned char* __restrict__ fb8p,
                                                 const unsigned char* __restrict__ fb8s,
                                                 float* __restrict__ part) {
    __shared__ __align__(16) unsigned char lds[2][BN * 128];   // 2 x 16KB
    const int bid = blockIdx.x;
    const int rb = bid / CS, cs = bid % CS;
    const int tid = threadIdx.x;
    const int lane = tid & 63;
    const int wid  = tid >> 6;                 // 0..3
    const int l31 = lane & 31, lhi = lane >> 5;
    const int rw = rb * 128 + wid * 32;        // this wave's 32 rows

    // staging: 4 issues x 16B per lane; dest linear, source slot-swizzled.
    int soff[4], dstoff[4];
    #pragma unroll
    for (int i = 0; i < 4; ++i) {
        int crow = wid * 32 + i * 8 + (lane >> 3);
        soff[i]   = crow * 128 + (((lane & 7) ^ (crow & 7)) << 4);
        dstoff[i] = (wid * 4 + i) * 1024 + (lane & 63) * 16;
    }

    // row fragments (B operand, scaled side): 8 x 8B
    long rf[8];
    #pragma unroll
    for (int ks = 0; ks < 8; ++ks)
        rf[ks] = *(const long*)(fb8s + (size_t)(rw + l31) * D + ks * 16 + lhi * 8);

    float rsum = 0.f;

    // prologue: stage tile 0 (ct = cs) into buf 0
    {
        const unsigned char* base = fb8p + (size_t)cs * (BN * 128);
        #pragma unroll
        for (int i = 0; i < 4; ++i)
            __builtin_amdgcn_global_load_lds(
                (const __attribute__((address_space(1))) unsigned int*)(base + soff[i]),
                (__attribute__((address_space(3))) unsigned int*)(&lds[0][dstoff[i]]),
                16, 0, 0);
    }
    asm volatile("s_waitcnt vmcnt(0)" ::: "memory");
    __builtin_amdgcn_s_barrier();

    int cur = 0;
    for (int t = 0; t < 5; ++t) {
        int ct = cs + t * CS;

        // prefetch next tile into the other buffer (flies across whole phase)
        if (t + 1 < 5) {
            const unsigned char* base = fb8p + ((size_t)ct + CS) * (BN * 128);
            #pragma unroll
            for (int i = 0; i < 4; ++i)
                __builtin_amdgcn_global_load_lds(
                    (const __attribute__((address_space(1))) unsigned int*)(base + soff[i]),
                    (__attribute__((address_space(3))) unsigned int*)(&lds[cur ^ 1][dstoff[i]]),
                    16, 0, 0);
        }

        f32x16 acc[4];
        #pragma unroll
        for (int i = 0; i < 4; ++i)
            #pragma unroll
            for (int e = 0; e < 16; ++e) acc[i][e] = -SC;

        __builtin_amdgcn_s_setprio(1);
        #pragma unroll
        for (int ks2 = 0; ks2 < 4; ++ks2) {
            #pragma unroll
            for (int cc = 0; cc < 4; ++cc) {
                int crow = cc * 32 + l31;
                l64x2 cf = *(const l64x2*)(&lds[cur][crow * 128 +
                               ((((lhi << 2) + ks2) ^ (crow & 7)) << 4)]);
                acc[cc] = __builtin_amdgcn_mfma_f32_32x32x16_fp8_fp8(cf.x, rf[ks2 * 2],     acc[cc], 0, 0, 0);
                acc[cc] = __builtin_amdgcn_mfma_f32_32x32x16_fp8_fp8(cf.y, rf[ks2 * 2 + 1], acc[cc], 0, 0, 0);
            }
        }
        __builtin_amdgcn_s_setprio(0);

        // epilogue: acc = (sim-1)*log2e/T already -> e = exp2(acc). Uniform.
        #pragma unroll
        for (int cc = 0; cc < 4; ++cc) {
            float p = 0.f;
            #pragma unroll
            for (int g = 0; g < 16; ++g)
                p += __builtin_amdgcn_exp2f(acc[cc][g]);
            rsum += p;
        }

        asm volatile("s_waitcnt vmcnt(0)" ::: "memory");
        __builtin_amdgcn_s_barrier();
        cur ^= 1;
    }

    // combine the two c-halves (lane and lane^32 hold same row, different cols)
    rsum += __shfl_xor(rsum, 32);
    if (lane < 32)
        part[(size_t)cs * N + rw + lane] = rsum;
}

// ---------------------------------------------------------------------------
// K4: per-row finalize: LSE (minus diag term) + positive term; block-reduce.
// ---------------------------------------------------------------------------
__global__ __launch_bounds__(256) void k_rowfin(const float* __restrict__ part,
                                                const float* __restrict__ ff,
                                                const float* __restrict__ S,
                                                const float* __restrict__ diag,
                                                const int* __restrict__ cnt,
                                                const long long* __restrict__ tgt,
                                                float* __restrict__ bsum) {
    __shared__ float sS[256];
    __shared__ float red[256];
    sS[threadIdx.x] = S[threadIdx.x];
    __syncthreads();
    int r = blockIdx.x * 256 + threadIdx.x;
    float se = 0.f;
    #pragma unroll
    for (int c = 0; c < CS; ++c) se += part[(size_t)c * N + r];
    se -= diag[r];
    float lse = logf(se) + 1.0f / TEMPERATURE;
    int lab = (r < NQ) ? (int)tgt[r] : ((r < NQ + KQ) ? 1 : 0);
    const float4* frow = (const float4*)(ff + (size_t)r * D);
    const float4* srow = (const float4*)(sS + lab * 128);
    float dS = 0.f;
    #pragma unroll
    for (int i = 0; i < 32; ++i) {
        float4 f = frow[i];
        float4 s = srow[i];
        dS += f.x * s.x + f.y * s.y + f.z * s.z + f.w * s.w;
    }
    float P = (float)(cnt[lab] - 1);
    // ||f||^2 == 1 exactly (features L2-normalized in f32)
    float mlpp = (dS - 1.0f) / (TEMPERATURE * P) - lse;
    red[threadIdx.x] = mlpp;
    __syncthreads();
    for (int s2 = 128; s2 > 0; s2 >>= 1) {
        if (threadIdx.x < s2) red[threadIdx.x] += red[threadIdx.x + s2];
        __syncthreads();
    }
    if (threadIdx.x == 0) bsum[blockIdx.x] = red[0];
}

// ---------------------------------------------------------------------------
// K5: final scalar.
// ---------------------------------------------------------------------------
__global__ __launch_bounds__(64) void k_final(const float* __restrict__ bsum,
                                              float* __restrict__ out) {
    float s = bsum[threadIdx.x];                 // RBF=65 > 64, lanes 0..63 valid
    if (threadIdx.x == 0) s += bsum[64];
    #pragma unroll
    for (int m = 1; m < 64; m <<= 1) s += __shfl_xor(s, m);
    if (threadIdx.x == 0) out[0] = -s / (float)N;
}

extern "C" void kernel_launch(void* const* d_in, const int* in_sizes, int n_in,
                              void* d_out, int out_size, void* d_ws, size_t ws_size,
                              hipStream_t stream) {
    const float* q       = (const float*)d_in[0];
    const float* ba      = (const float*)d_in[1];
    const float* nb      = (const float*)d_in[2];
    const long long* tgt = (const long long*)d_in[3];
    char* ws = (char*)d_ws;
    float*         ff   = (float*)(ws + OFF_F32);
    unsigned char* fb8p = (unsigned char*)(ws + OFF_8P);
    unsigned char* fb8s = (unsigned char*)(ws + OFF_8S);
    float*         diag = (float*)(ws + OFF_DIAG);
    float*         part = (float*)(ws + OFF_PART);
    float*         lp   = (float*)(ws + OFF_LP);
    float*         S    = (float*)(ws + OFF_S);
    int*           cnt  = (int*)(ws + OFF_CNT);
    float*         bsum = (float*)(ws + OFF_BSUM);

    k_prep  <<<260,      256, 0, stream>>>(q, ba, nb, tgt, ff, fb8p, fb8s, diag, lp);
    k_lsum_b<<<1,        256, 0, stream>>>(lp, tgt, S, cnt);
    k_main  <<<RBM * CS, 256, 0, stream>>>(fb8p, fb8s, part);
    k_rowfin<<<RBF,      256, 0, stream>>>(part, ff, S, diag, cnt, tgt, bsum);
    k_final <<<1,         64, 0, stream>>>(bsum, (float*)d_out);
}

// Round 7
// 80.208 us; speedup vs baseline: 1.7754x; 1.1996x over previous
//
#include <hip/hip_runtime.h>
#include <hip/hip_bf16.h>
#include <stdint.h>

#define TEMPERATURE 0.07f
#define SC 20.6099312f   // log2(e)/T

constexpr int NQ = 256;
constexpr int KQ = 8192;
constexpr int D  = 128;
constexpr int N  = NQ + 2 * KQ;   // 16640
constexpr int CS = 26;            // column splits (130 tiles / 26 = exactly 5 per block)
constexpr int BN = 128;           // columns per tile (fp8 tile = 16KB)
constexpr int NT = N / BN;        // 130 column tiles
constexpr int RBM = N / 128;      // 130 row blocks for k_main
constexpr int RBF = N / 256;      // 65 blocks for k_rowfin

typedef float f32x16 __attribute__((ext_vector_type(16)));
typedef int   i32x4  __attribute__((ext_vector_type(4)));
typedef int   i32x8  __attribute__((ext_vector_type(8)));

// ---- workspace layout (bytes) ----
constexpr size_t OFF_F32  = 0;                                    // float feat [N][D]
constexpr size_t OFF_8    = OFF_F32  + (size_t)N * D * 4;         // fp8 feat (A side) [N][128]
constexpr size_t OFF_8S   = OFF_8    + (size_t)N * D;             // fp8 feat * SC (B side) [N][128]
constexpr size_t OFF_PART = OFF_8S   + (size_t)N * D;             // partials [CS][N]
constexpr size_t OFF_LP   = OFF_PART + (size_t)CS * N * 4;        // label partials [260][2][128]
constexpr size_t OFF_S    = OFF_LP   + (size_t)260 * 2 * 128 * 4; // S [2][128]
constexpr size_t OFF_CNT  = OFF_S    + 2 * 128 * 4;               // counts [2] int
constexpr size_t OFF_BSUM = OFF_CNT  + 16;                        // blocksum [65]

// ---------------------------------------------------------------------------
// K1: normalize features; emit f32 + two natural-row-major fp8 copies
// (unscaled for the LDS/A side, SC-prescaled for the register/B side);
// and per-label per-dim partial sums. 260 blocks x 64 rows.
// ---------------------------------------------------------------------------
__global__ __launch_bounds__(256) void k_prep(const float* __restrict__ q,
                                              const float* __restrict__ ba,
                                              const float* __restrict__ nb,
                                              const long long* __restrict__ tgt,
                                              float* __restrict__ ff,
                                              unsigned char* __restrict__ fb8,
                                              unsigned char* __restrict__ fb8s,
                                              float* __restrict__ lp) {
    __shared__ float red[4][2][128];
    int wid = threadIdx.x >> 6, lane = threadIdx.x & 63;
    int rbase = blockIdx.x * 64 + wid * 16;
    float s0x = 0.f, s0y = 0.f, s1x = 0.f, s1y = 0.f;
    for (int i = 0; i < 16; ++i) {
        int r = rbase + i;
        const float* src = (r < NQ) ? (q + (size_t)r * D)
                         : (r < NQ + KQ) ? (ba + (size_t)(r - NQ) * D)
                         : (nb + (size_t)(r - NQ - KQ) * D);
        float2 v = *(const float2*)(src + lane * 2);
        float a = v.x, b = v.y;
        int lab;
        if (r < NQ) {
            float ss = a * a + b * b;
            #pragma unroll
            for (int m = 1; m < 64; m <<= 1) ss += __shfl_xor(ss, m);
            float scale = 1.0f / fmaxf(sqrtf(ss), 1e-12f);
            a *= scale; b *= scale;
            lab = (int)tgt[r];
        } else {
            lab = (r < NQ + KQ) ? 1 : 0;
        }
        *(float2*)(ff + (size_t)r * D + lane * 2) = make_float2(a, b);
        int w8  = __builtin_amdgcn_cvt_pk_fp8_f32(a, b, 0, false);
        int w8s = __builtin_amdgcn_cvt_pk_fp8_f32(a * SC, b * SC, 0, false);
        *(unsigned short*)(fb8  + (size_t)r * D + lane * 2) = (unsigned short)w8;
        *(unsigned short*)(fb8s + (size_t)r * D + lane * 2) = (unsigned short)w8s;
        if (lab) { s1x += a; s1y += b; } else { s0x += a; s0y += b; }
    }
    red[wid][0][lane * 2]     = s0x;
    red[wid][0][lane * 2 + 1] = s0y;
    red[wid][1][lane * 2]     = s1x;
    red[wid][1][lane * 2 + 1] = s1y;
    __syncthreads();
    int lab2 = threadIdx.x >> 7, d = threadIdx.x & 127;
    float s = red[0][lab2][d] + red[1][lab2][d] + red[2][lab2][d] + red[3][lab2][d];
    lp[((size_t)blockIdx.x * 2 + lab2) * 128 + d] = s;
}

// ---------------------------------------------------------------------------
// K2: stage-2 label-sum reduction + label counts.
// ---------------------------------------------------------------------------
__global__ __launch_bounds__(256) void k_lsum_b(const float* __restrict__ lp,
                                                const long long* __restrict__ tgt,
                                                float* __restrict__ S,
                                                int* __restrict__ cnt) {
    int lab = threadIdx.x >> 7;       // 0 or 1
    int d   = threadIdx.x & 127;
    float s[4] = {0.f, 0.f, 0.f, 0.f};
    for (int b = 0; b < 260; b += 4) {
        #pragma unroll
        for (int j = 0; j < 4; ++j)
            s[j] += lp[((size_t)(b + j) * 2 + lab) * 128 + d];
    }
    S[lab * 128 + d] = (s[0] + s[1]) + (s[2] + s[3]);
    if (threadIdx.x < 64) {
        int c = 0;
        #pragma unroll
        for (int i = 0; i < 4; ++i) c += (int)tgt[threadIdx.x + 64 * i];
        #pragma unroll
        for (int m = 1; m < 64; m <<= 1) c += __shfl_xor(c, m);
        if (threadIdx.x == 0) { cnt[0] = (NQ - c) + KQ; cnt[1] = c + KQ; }
    }
}

// ---------------------------------------------------------------------------
// K3: main fused MX-fp8 GEMM + exp row-sum.
//   Grid 130*26 = 3380 blocks, 256 threads (4 waves x 32 rows = 128 rows).
//   mfma_scale_f32_32x32x64_f8f6f4 with unit scales (E8M0 127) = plain fp8
//   matmul at 2x the non-scaled rate. rf side prescaled by SC, acc init -SC
//   -> epilogue is a bare v_exp. Diagonal subtracted later in k_rowfin.
//   LDS: 2 rows per 256B line, 16B slot p = ((row&1)*8+chunk) ^ ((row>>1)&15)
//   -> every quarter-wave of a ds_read_b128 hits 16 distinct slots (0-conflict,
//   same structure as the verified bf16 R5 layout). Linear-dest staging with
//   the matching source permutation.
// ---------------------------------------------------------------------------
__global__ __launch_bounds__(256, 4) void k_main(const unsigned char* __restrict__ fb8,
                                                 const unsigned char* __restrict__ fb8s,
                                                 float* __restrict__ part) {
    __shared__ __align__(16) unsigned char lds[2][BN * 128];   // 2 x 16KB
    const int bid = blockIdx.x;
    const int rb = bid / CS, cs = bid % CS;
    const int tid = threadIdx.x;
    const int lane = tid & 63;
    const int wid  = tid >> 6;                 // 0..3
    const int l31 = lane & 31, lhi = lane >> 5;
    const int rw = rb * 128 + wid * 32;        // this wave's 32 rows

    // staging: 4 issues x 16B per thread; dest linear (flat*16), source
    // offset inverts the line/slot swizzle.
    int soff[4];
    #pragma unroll
    for (int i = 0; i < 4; ++i) {
        int flat = i * 256 + tid;
        int line = flat >> 4, p = flat & 15;
        int pl = p ^ (line & 15);
        soff[i] = (2 * line + (pl >> 3)) * 128 + (pl & 7) * 16;
    }

    // rf: B operand (scaled side), natural rows: 2 K-steps x 32B
    i32x8 rf[2];
    #pragma unroll
    for (int s = 0; s < 2; ++s)
        rf[s] = *(const i32x8*)(fb8s + (size_t)(rw + l31) * D + s * 64 + lhi * 32);

    float rsum = 0.f;

    // prologue: stage tile 0 (ct = cs) into buf 0
    {
        const unsigned char* base = fb8 + (size_t)cs * (BN * 128);
        #pragma unroll
        for (int i = 0; i < 4; ++i)
            __builtin_amdgcn_global_load_lds(
                (const __attribute__((address_space(1))) unsigned int*)(base + soff[i]),
                (__attribute__((address_space(3))) unsigned int*)(&lds[0][(i * 256 + tid) * 16]),
                16, 0, 0);
    }
    asm volatile("s_waitcnt vmcnt(0)" ::: "memory");
    __builtin_amdgcn_s_barrier();

    int cur = 0;
    for (int t = 0; t < 5; ++t) {
        int ct = cs + t * CS;

        // prefetch next tile into the other buffer (flies across whole phase)
        if (t + 1 < 5) {
            const unsigned char* base = fb8 + ((size_t)ct + CS) * (BN * 128);
            #pragma unroll
            for (int i = 0; i < 4; ++i)
                __builtin_amdgcn_global_load_lds(
                    (const __attribute__((address_space(1))) unsigned int*)(base + soff[i]),
                    (__attribute__((address_space(3))) unsigned int*)(&lds[cur ^ 1][(i * 256 + tid) * 16]),
                    16, 0, 0);
        }

        f32x16 acc[4];
        #pragma unroll
        for (int i = 0; i < 4; ++i)
            #pragma unroll
            for (int e = 0; e < 16; ++e) acc[i][e] = -SC;

        __builtin_amdgcn_s_setprio(1);
        #pragma unroll
        for (int s = 0; s < 2; ++s) {
            #pragma unroll
            for (int cc = 0; cc < 4; ++cc) {
                int crow = cc * 32 + l31;
                int line = crow >> 1;
                int pb = ((crow & 1) << 3) + s * 4 + lhi * 2;
                const unsigned char* lb = &lds[cur][line * 256];
                i32x4 lo = *(const i32x4*)(lb + ((pb    ) ^ (line & 15)) * 16);
                i32x4 hi = *(const i32x4*)(lb + ((pb + 1) ^ (line & 15)) * 16);
                i32x8 a = {lo[0], lo[1], lo[2], lo[3], hi[0], hi[1], hi[2], hi[3]};
                acc[cc] = __builtin_amdgcn_mfma_scale_f32_32x32x64_f8f6f4(
                    a, rf[s], acc[cc], 0, 0, 0, 0x7f7f7f7f, 0, 0x7f7f7f7f);
            }
        }
        __builtin_amdgcn_s_setprio(0);

        // epilogue: acc = (sim-1)*log2e/T -> e = exp2(acc). Uniform, branch-free.
        #pragma unroll
        for (int cc = 0; cc < 4; ++cc) {
            float p = 0.f;
            #pragma unroll
            for (int g = 0; g < 16; ++g)
                p += __builtin_amdgcn_exp2f(acc[cc][g]);
            rsum += p;
        }

        asm volatile("s_waitcnt vmcnt(0)" ::: "memory");
        __builtin_amdgcn_s_barrier();
        cur ^= 1;
    }

    // combine the two c-halves (lane and lane^32 hold same row, different cols)
    rsum += __shfl_xor(rsum, 32);
    if (lane < 32)
        part[(size_t)cs * N + rw + lane] = rsum;
}

// ---------------------------------------------------------------------------
// K4: per-row finalize: LSE (minus exact fp8 diag replica) + positive term.
// ---------------------------------------------------------------------------
__global__ __launch_bounds__(256) void k_rowfin(const float* __restrict__ part,
                                                const float* __restrict__ ff,
                                                const float* __restrict__ S,
                                                const int* __restrict__ cnt,
                                                const long long* __restrict__ tgt,
                                                float* __restrict__ bsum) {
    __shared__ float sS[256];
    __shared__ float red[256];
    sS[threadIdx.x] = S[threadIdx.x];
    __syncthreads();
    int r = blockIdx.x * 256 + threadIdx.x;
    float se = 0.f;
    #pragma unroll
    for (int c = 0; c < CS; ++c) se += part[(size_t)c * N + r];
    int lab = (r < NQ) ? (int)tgt[r] : ((r < NQ + KQ) ? 1 : 0);
    const float4* frow = (const float4*)(ff + (size_t)r * D);
    const float4* srow = (const float4*)(sS + lab * 128);
    float dS = 0.f, dd = 0.f;
    #pragma unroll
    for (int i = 0; i < 32; ++i) {
        float4 f = frow[i];
        float4 s = srow[i];
        dS += f.x * s.x + f.y * s.y + f.z * s.z + f.w * s.w;
        // exact replica of the MFMA's diagonal contribution (same cvt ops)
        int wa  = __builtin_amdgcn_cvt_pk_fp8_f32(f.x, f.y, 0, false);
        int wb  = __builtin_amdgcn_cvt_pk_fp8_f32(f.z, f.w, 0, false);
        int wsa = __builtin_amdgcn_cvt_pk_fp8_f32(f.x * SC, f.y * SC, 0, false);
        int wsb = __builtin_amdgcn_cvt_pk_fp8_f32(f.z * SC, f.w * SC, 0, false);
        dd += __builtin_amdgcn_cvt_f32_fp8(wa, 0) * __builtin_amdgcn_cvt_f32_fp8(wsa, 0)
            + __builtin_amdgcn_cvt_f32_fp8(wa, 1) * __builtin_amdgcn_cvt_f32_fp8(wsa, 1)
            + __builtin_amdgcn_cvt_f32_fp8(wb, 0) * __builtin_amdgcn_cvt_f32_fp8(wsb, 0)
            + __builtin_amdgcn_cvt_f32_fp8(wb, 1) * __builtin_amdgcn_cvt_f32_fp8(wsb, 1);
    }
    se -= __builtin_amdgcn_exp2f(dd - SC);
    float lse = logf(se) + 1.0f / TEMPERATURE;
    float P = (float)(cnt[lab] - 1);
    // ||f||^2 == 1 exactly (features L2-normalized in f32)
    float mlpp = (dS - 1.0f) / (TEMPERATURE * P) - lse;
    red[threadIdx.x] = mlpp;
    __syncthreads();
    for (int s2 = 128; s2 > 0; s2 >>= 1) {
        if (threadIdx.x < s2) red[threadIdx.x] += red[threadIdx.x + s2];
        __syncthreads();
    }
    if (threadIdx.x == 0) bsum[blockIdx.x] = red[0];
}

// ---------------------------------------------------------------------------
// K5: final scalar.
// ---------------------------------------------------------------------------
__global__ __launch_bounds__(64) void k_final(const float* __restrict__ bsum,
                                              float* __restrict__ out) {
    float s = bsum[threadIdx.x];                 // RBF=65 > 64, lanes 0..63 valid
    if (threadIdx.x == 0) s += bsum[64];
    #pragma unroll
    for (int m = 1; m < 64; m <<= 1) s += __shfl_xor(s, m);
    if (threadIdx.x == 0) out[0] = -s / (float)N;
}

extern "C" void kernel_launch(void* const* d_in, const int* in_sizes, int n_in,
                              void* d_out, int out_size, void* d_ws, size_t ws_size,
                              hipStream_t stream) {
    const float* q       = (const float*)d_in[0];
    const float* ba      = (const float*)d_in[1];
    const float* nb      = (const float*)d_in[2];
    const long long* tgt = (const long long*)d_in[3];
    char* ws = (char*)d_ws;
    float*         ff   = (float*)(ws + OFF_F32);
    unsigned char* fb8  = (unsigned char*)(ws + OFF_8);
    unsigned char* fb8s = (unsigned char*)(ws + OFF_8S);
    float*         part = (float*)(ws + OFF_PART);
    float*         lp   = (float*)(ws + OFF_LP);
    float*         S    = (float*)(ws + OFF_S);
    int*           cnt  = (int*)(ws + OFF_CNT);
    float*         bsum = (float*)(ws + OFF_BSUM);

    k_prep  <<<260,      256, 0, stream>>>(q, ba, nb, tgt, ff, fb8, fb8s, lp);
    k_lsum_b<<<1,        256, 0, stream>>>(lp, tgt, S, cnt);
    k_main  <<<RBM * CS, 256, 0, stream>>>(fb8, fb8s, part);
    k_rowfin<<<RBF,      256, 0, stream>>>(part, ff, S, cnt, tgt, bsum);
    k_final <<<1,         64, 0, stream>>>(bsum, (float*)d_out);
}

// Round 8
// 77.954 us; speedup vs baseline: 1.8267x; 1.0289x over previous
//
#include <hip/hip_runtime.h>
#include <hip/hip_bf16.h>
#include <stdint.h>

#define TEMPERATURE 0.07f
#define SC 20.6099312f   // log2(e)/T

constexpr int NQ = 256;
constexpr int KQ = 8192;
constexpr int D  = 128;
constexpr int N  = NQ + 2 * KQ;   // 16640
constexpr int CS = 26;            // column splits (130 tiles / 26 = exactly 5 per block)
constexpr int BN = 128;           // columns per tile (fp8 tile = 16KB)
constexpr int NT = N / BN;        // 130 column tiles
constexpr int RBM = N / 128;      // 130 row blocks for k_main
constexpr int RBF = N / 256;      // 65 blocks for k_rowfin

typedef float f32x16 __attribute__((ext_vector_type(16)));
typedef int   i32x4  __attribute__((ext_vector_type(4)));
typedef int   i32x8  __attribute__((ext_vector_type(8)));

// ---- workspace layout (bytes) ----
constexpr size_t OFF_F32  = 0;                                    // float feat [N][D]
constexpr size_t OFF_8    = OFF_F32  + (size_t)N * D * 4;         // fp8 feat (A side) [N][128]
constexpr size_t OFF_8S   = OFF_8    + (size_t)N * D;             // fp8 feat * SC (B side) [N][128]
constexpr size_t OFF_PART = OFF_8S   + (size_t)N * D;             // partials [CS][N]
constexpr size_t OFF_LP   = OFF_PART + (size_t)CS * N * 4;        // label partials [260][2][128]
constexpr size_t OFF_BSUM = OFF_LP   + (size_t)260 * 2 * 128 * 4; // blocksum [65]

// ---------------------------------------------------------------------------
// K1: normalize features; emit f32 + two natural-row-major fp8 copies
// (unscaled for the LDS/A side, SC-prescaled for the register/B side);
// and per-label per-dim partial sums. 260 blocks x 64 rows.
// ---------------------------------------------------------------------------
__global__ __launch_bounds__(256) void k_prep(const float* __restrict__ q,
                                              const float* __restrict__ ba,
                                              const float* __restrict__ nb,
                                              const long long* __restrict__ tgt,
                                              float* __restrict__ ff,
                                              unsigned char* __restrict__ fb8,
                                              unsigned char* __restrict__ fb8s,
                                              float* __restrict__ lp) {
    __shared__ float red[4][2][128];
    int wid = threadIdx.x >> 6, lane = threadIdx.x & 63;
    int rbase = blockIdx.x * 64 + wid * 16;
    float s0x = 0.f, s0y = 0.f, s1x = 0.f, s1y = 0.f;
    for (int i = 0; i < 16; ++i) {
        int r = rbase + i;
        const float* src = (r < NQ) ? (q + (size_t)r * D)
                         : (r < NQ + KQ) ? (ba + (size_t)(r - NQ) * D)
                         : (nb + (size_t)(r - NQ - KQ) * D);
        float2 v = *(const float2*)(src + lane * 2);
        float a = v.x, b = v.y;
        int lab;
        if (r < NQ) {
            float ss = a * a + b * b;
            #pragma unroll
            for (int m = 1; m < 64; m <<= 1) ss += __shfl_xor(ss, m);
            float scale = 1.0f / fmaxf(sqrtf(ss), 1e-12f);
            a *= scale; b *= scale;
            lab = (int)tgt[r];
        } else {
            lab = (r < NQ + KQ) ? 1 : 0;
        }
        *(float2*)(ff + (size_t)r * D + lane * 2) = make_float2(a, b);
        int w8  = __builtin_amdgcn_cvt_pk_fp8_f32(a, b, 0, false);
        int w8s = __builtin_amdgcn_cvt_pk_fp8_f32(a * SC, b * SC, 0, false);
        *(unsigned short*)(fb8  + (size_t)r * D + lane * 2) = (unsigned short)w8;
        *(unsigned short*)(fb8s + (size_t)r * D + lane * 2) = (unsigned short)w8s;
        if (lab) { s1x += a; s1y += b; } else { s0x += a; s0y += b; }
    }
    red[wid][0][lane * 2]     = s0x;
    red[wid][0][lane * 2 + 1] = s0y;
    red[wid][1][lane * 2]     = s1x;
    red[wid][1][lane * 2 + 1] = s1y;
    __syncthreads();
    int lab2 = threadIdx.x >> 7, d = threadIdx.x & 127;
    float s = red[0][lab2][d] + red[1][lab2][d] + red[2][lab2][d] + red[3][lab2][d];
    lp[((size_t)blockIdx.x * 2 + lab2) * 128 + d] = s;
}

// ---------------------------------------------------------------------------
// K3: main fused MX-fp8 GEMM + exp row-sum.
//   Grid 130*26 = 3380 blocks, 256 threads = 4 waves in a 2x2 grid:
//   each wave owns 64 rows x 64 cols (A-operand reused across 2 row-groups
//   -> 1 ds_read_b128 per MFMA). mfma_scale 32x32x64 fp8, unit scales.
//   rf prescaled by SC, acc init -SC -> epilogue is a bare v_exp.
//   LDS: 2 rows per 256B line, slot p = ((row&1)*8+chunk) ^ ((row>>1)&15):
//   16 distinct slots per quarter-wave (PMC-verified 0 conflicts in R7).
// ---------------------------------------------------------------------------
__global__ __launch_bounds__(256, 3) void k_main(const unsigned char* __restrict__ fb8,
                                                 const unsigned char* __restrict__ fb8s,
                                                 float* __restrict__ part) {
    __shared__ __align__(16) unsigned char lds[2][BN * 128];   // 2 x 16KB
    const int bid = blockIdx.x;
    const int rb = bid / CS, cs = bid % CS;
    const int tid = threadIdx.x;
    const int lane = tid & 63;
    const int wid  = tid >> 6;                 // 0..3
    const int wr = wid >> 1, wc = wid & 1;     // 2x2 wave grid
    const int l31 = lane & 31, lhi = lane >> 5;
    const int rw = rb * 128 + wr * 64;         // this wave's 64 rows

    // staging: 4 issues x 16B per thread; dest linear (flat*16), source
    // offset inverts the line/slot swizzle.
    int soff[4];
    #pragma unroll
    for (int i = 0; i < 4; ++i) {
        int flat = i * 256 + tid;
        int line = flat >> 4, p = flat & 15;
        int pl = p ^ (line & 15);
        soff[i] = (2 * line + (pl >> 3)) * 128 + (pl & 7) * 16;
    }

    // rf: B operand (scaled side), 2 row-groups x 2 K-steps x 32B
    i32x8 rf[2][2];
    #pragma unroll
    for (int rs = 0; rs < 2; ++rs)
        #pragma unroll
        for (int s = 0; s < 2; ++s)
            rf[rs][s] = *(const i32x8*)(fb8s + (size_t)(rw + rs * 32 + l31) * D + s * 64 + lhi * 32);

    float rsum[2] = {0.f, 0.f};

    // prologue: stage tile 0 (ct = cs) into buf 0
    {
        const unsigned char* base = fb8 + (size_t)cs * (BN * 128);
        #pragma unroll
        for (int i = 0; i < 4; ++i)
            __builtin_amdgcn_global_load_lds(
                (const __attribute__((address_space(1))) unsigned int*)(base + soff[i]),
                (__attribute__((address_space(3))) unsigned int*)(&lds[0][(i * 256 + tid) * 16]),
                16, 0, 0);
    }
    asm volatile("s_waitcnt vmcnt(0)" ::: "memory");
    __builtin_amdgcn_s_barrier();

    int cur = 0;
    for (int t = 0; t < 5; ++t) {
        int ct = cs + t * CS;

        // prefetch next tile into the other buffer (flies across whole phase)
        if (t + 1 < 5) {
            const unsigned char* base = fb8 + ((size_t)ct + CS) * (BN * 128);
            #pragma unroll
            for (int i = 0; i < 4; ++i)
                __builtin_amdgcn_global_load_lds(
                    (const __attribute__((address_space(1))) unsigned int*)(base + soff[i]),
                    (__attribute__((address_space(3))) unsigned int*)(&lds[cur ^ 1][(i * 256 + tid) * 16]),
                    16, 0, 0);
        }

        f32x16 acc[2][2];
        #pragma unroll
        for (int i = 0; i < 2; ++i)
            #pragma unroll
            for (int j = 0; j < 2; ++j)
                #pragma unroll
                for (int e = 0; e < 16; ++e) acc[i][j][e] = -SC;

        __builtin_amdgcn_s_setprio(1);
        #pragma unroll
        for (int s = 0; s < 2; ++s) {
            #pragma unroll
            for (int cc = 0; cc < 2; ++cc) {
                int crow = wc * 64 + cc * 32 + l31;
                int line = crow >> 1;
                int pb = ((crow & 1) << 3) + s * 4 + lhi * 2;
                const unsigned char* lb = &lds[cur][line * 256];
                i32x4 lo = *(const i32x4*)(lb + ((pb    ) ^ (line & 15)) * 16);
                i32x4 hi = *(const i32x4*)(lb + ((pb + 1) ^ (line & 15)) * 16);
                i32x8 a = {lo[0], lo[1], lo[2], lo[3], hi[0], hi[1], hi[2], hi[3]};
                acc[cc][0] = __builtin_amdgcn_mfma_scale_f32_32x32x64_f8f6f4(
                    a, rf[0][s], acc[cc][0], 0, 0, 0, 0x7f7f7f7f, 0, 0x7f7f7f7f);
                acc[cc][1] = __builtin_amdgcn_mfma_scale_f32_32x32x64_f8f6f4(
                    a, rf[1][s], acc[cc][1], 0, 0, 0, 0x7f7f7f7f, 0, 0x7f7f7f7f);
            }
        }
        __builtin_amdgcn_s_setprio(0);

        // epilogue: acc = (sim-1)*log2e/T -> e = exp2(acc). Uniform, branch-free.
        #pragma unroll
        for (int cc = 0; cc < 2; ++cc) {
            #pragma unroll
            for (int rs = 0; rs < 2; ++rs) {
                float p = 0.f;
                #pragma unroll
                for (int g = 0; g < 16; ++g)
                    p += __builtin_amdgcn_exp2f(acc[cc][rs][g]);
                rsum[rs] += p;
            }
        }

        asm volatile("s_waitcnt vmcnt(0)" ::: "memory");
        __builtin_amdgcn_s_barrier();
        cur ^= 1;
    }

    // combine the two c-halves (lane and lane^32 hold same row, different cols),
    // then combine the two col-half waves via part (each writes its own cs slot?
    // no: both col-half waves share rows -> reduce across wc via LDS).
    rsum[0] += __shfl_xor(rsum[0], 32);
    rsum[1] += __shfl_xor(rsum[1], 32);
    __shared__ float xred[2][2][32];   // [wr][rs][row]  (wc=0 writes, wc=1 adds)
    if (wc == 0 && lane < 32) {
        xred[wr][0][lane] = rsum[0];
        xred[wr][1][lane] = rsum[1];
    }
    __syncthreads();
    if (wc == 1 && lane < 32) {
        part[(size_t)cs * N + rw + lane]      = xred[wr][0][lane] + rsum[0];
        part[(size_t)cs * N + rw + 32 + lane] = xred[wr][1][lane] + rsum[1];
    }
}

// ---------------------------------------------------------------------------
// K4: per-row finalize. Each block first (redundantly) reduces the label
// partial sums lp -> S and recomputes counts (deterministic), then computes
// LSE (minus exact fp8 diag replica) + positive term; block-reduce.
// ---------------------------------------------------------------------------
__global__ __launch_bounds__(256) void k_rowfin(const float* __restrict__ part,
                                                const float* __restrict__ ff,
                                                const float* __restrict__ lp,
                                                const long long* __restrict__ tgt,
                                                float* __restrict__ bsum) {
    __shared__ float sS[256];
    __shared__ float red[256];
    __shared__ int scnt[2];
    {   // S reduction (redundant per block; fixed order -> deterministic)
        int lab = threadIdx.x >> 7, d = threadIdx.x & 127;
        float s[4] = {0.f, 0.f, 0.f, 0.f};
        for (int b = 0; b < 260; b += 4) {
            #pragma unroll
            for (int j = 0; j < 4; ++j)
                s[j] += lp[((size_t)(b + j) * 2 + lab) * 128 + d];
        }
        sS[threadIdx.x] = (s[0] + s[1]) + (s[2] + s[3]);
        if (threadIdx.x < 64) {
            int c = 0;
            #pragma unroll
            for (int i = 0; i < 4; ++i) c += (int)tgt[threadIdx.x + 64 * i];
            #pragma unroll
            for (int m = 1; m < 64; m <<= 1) c += __shfl_xor(c, m);
            if (threadIdx.x == 0) { scnt[0] = (NQ - c) + KQ; scnt[1] = c + KQ; }
        }
    }
    __syncthreads();
    int r = blockIdx.x * 256 + threadIdx.x;
    float se = 0.f;
    #pragma unroll
    for (int c = 0; c < CS; ++c) se += part[(size_t)c * N + r];
    int lab = (r < NQ) ? (int)tgt[r] : ((r < NQ + KQ) ? 1 : 0);
    const float4* frow = (const float4*)(ff + (size_t)r * D);
    const float4* srow = (const float4*)(sS + lab * 128);
    float dS = 0.f, dd = 0.f;
    #pragma unroll
    for (int i = 0; i < 32; ++i) {
        float4 f = frow[i];
        float4 s = srow[i];
        dS += f.x * s.x + f.y * s.y + f.z * s.z + f.w * s.w;
        // exact replica of the MFMA's diagonal contribution (same cvt ops)
        int wa  = __builtin_amdgcn_cvt_pk_fp8_f32(f.x, f.y, 0, false);
        int wb  = __builtin_amdgcn_cvt_pk_fp8_f32(f.z, f.w, 0, false);
        int wsa = __builtin_amdgcn_cvt_pk_fp8_f32(f.x * SC, f.y * SC, 0, false);
        int wsb = __builtin_amdgcn_cvt_pk_fp8_f32(f.z * SC, f.w * SC, 0, false);
        dd += __builtin_amdgcn_cvt_f32_fp8(wa, 0) * __builtin_amdgcn_cvt_f32_fp8(wsa, 0)
            + __builtin_amdgcn_cvt_f32_fp8(wa, 1) * __builtin_amdgcn_cvt_f32_fp8(wsa, 1)
            + __builtin_amdgcn_cvt_f32_fp8(wb, 0) * __builtin_amdgcn_cvt_f32_fp8(wsb, 0)
            + __builtin_amdgcn_cvt_f32_fp8(wb, 1) * __builtin_amdgcn_cvt_f32_fp8(wsb, 1);
    }
    se -= __builtin_amdgcn_exp2f(dd - SC);
    float lse = logf(se) + 1.0f / TEMPERATURE;
    float P = (float)(scnt[lab] - 1);
    // ||f||^2 == 1 exactly (features L2-normalized in f32)
    float mlpp = (dS - 1.0f) / (TEMPERATURE * P) - lse;
    red[threadIdx.x] = mlpp;
    __syncthreads();
    for (int s2 = 128; s2 > 0; s2 >>= 1) {
        if (threadIdx.x < s2) red[threadIdx.x] += red[threadIdx.x + s2];
        __syncthreads();
    }
    if (threadIdx.x == 0) bsum[blockIdx.x] = red[0];
}

// ---------------------------------------------------------------------------
// K5: final scalar.
// ---------------------------------------------------------------------------
__global__ __launch_bounds__(64) void k_final(const float* __restrict__ bsum,
                                              float* __restrict__ out) {
    float s = bsum[threadIdx.x];                 // RBF=65 > 64, lanes 0..63 valid
    if (threadIdx.x == 0) s += bsum[64];
    #pragma unroll
    for (int m = 1; m < 64; m <<= 1) s += __shfl_xor(s, m);
    if (threadIdx.x == 0) out[0] = -s / (float)N;
}

extern "C" void kernel_launch(void* const* d_in, const int* in_sizes, int n_in,
                              void* d_out, int out_size, void* d_ws, size_t ws_size,
                              hipStream_t stream) {
    const float* q       = (const float*)d_in[0];
    const float* ba      = (const float*)d_in[1];
    const float* nb      = (const float*)d_in[2];
    const long long* tgt = (const long long*)d_in[3];
    char* ws = (char*)d_ws;
    float*         ff   = (float*)(ws + OFF_F32);
    unsigned char* fb8  = (unsigned char*)(ws + OFF_8);
    unsigned char* fb8s = (unsigned char*)(ws + OFF_8S);
    float*         part = (float*)(ws + OFF_PART);
    float*         lp   = (float*)(ws + OFF_LP);
    float*         bsum = (float*)(ws + OFF_BSUM);

    k_prep  <<<260,      256, 0, stream>>>(q, ba, nb, tgt, ff, fb8, fb8s, lp);
    k_main  <<<RBM * CS, 256, 0, stream>>>(fb8, fb8s, part);
    k_rowfin<<<RBF,      256, 0, stream>>>(part, ff, lp, tgt, bsum);
    k_final <<<1,         64, 0, stream>>>(bsum, (float*)d_out);
}